// Round 1
// baseline (2791.809 us; speedup 1.0000x reference)
//
#include <hip/hip_runtime.h>

#define BM 128
#define BN 128
#define BK 32

constexpr int MM = 65536;   // batch
constexpr int KK = 512;     // inner dim
constexpr int NN = 512;     // out dim per layer

// C[M,N] = act(A[M,K] @ W[N,K]^T + bias[N])
template<bool RELU>
__global__ __launch_bounds__(256, 2) void gemm_bias_kernel(
    const float* __restrict__ A, const float* __restrict__ W,
    const float* __restrict__ bias, float* __restrict__ C) {
  // stride BK+2 = 34 floats: 8B-aligned for float2, and 8*34 % 32 = 16
  // -> micro-tile rows (8 apart) split banks into 2 groups: 2-way aliasing = free (m136)
  __shared__ float As[BM][BK + 2];
  __shared__ float Bs[BN][BK + 2];
  const int tid = threadIdx.x;
  const int tx = tid & 15;   // 16 cols of threads
  const int ty = tid >> 4;   // 16 rows of threads
  const int bm = blockIdx.x;
  const int bn = blockIdx.y;
  const float* Ab = A + (size_t)bm * BM * KK;
  const float* Wb = W + (size_t)bn * BN * KK;

  float acc[8][8] = {};

  for (int k0 = 0; k0 < KK; k0 += BK) {
    // stage 128x32 A-tile and W-tile: 1024 float4 each, 4 per thread
#pragma unroll
    for (int t = 0; t < 4; ++t) {
      int s = tid + t * 256;
      int row = s >> 3;          // 0..127
      int kc = (s & 7) << 2;     // 0,4,..,28
      float4 va = *(const float4*)(Ab + (size_t)row * KK + k0 + kc);
      float4 vb = *(const float4*)(Wb + (size_t)row * KK + k0 + kc);
      *(float2*)&As[row][kc]     = make_float2(va.x, va.y);
      *(float2*)&As[row][kc + 2] = make_float2(va.z, va.w);
      *(float2*)&Bs[row][kc]     = make_float2(vb.x, vb.y);
      *(float2*)&Bs[row][kc + 2] = make_float2(vb.z, vb.w);
    }
    __syncthreads();
#pragma unroll 4
    for (int kk = 0; kk < BK; kk += 2) {
      float2 a[8], b[8];
#pragma unroll
      for (int i = 0; i < 8; ++i) a[i] = *(const float2*)&As[ty * 8 + i][kk];
#pragma unroll
      for (int j = 0; j < 8; ++j) b[j] = *(const float2*)&Bs[tx * 8 + j][kk];
#pragma unroll
      for (int i = 0; i < 8; ++i)
#pragma unroll
        for (int j = 0; j < 8; ++j)
          acc[i][j] += a[i].x * b[j].x + a[i].y * b[j].y;
    }
    __syncthreads();
  }

  const int col0 = bn * BN + tx * 8;
#pragma unroll
  for (int i = 0; i < 8; ++i) {
    size_t row = (size_t)bm * BM + ty * 8 + i;
    float out[8];
#pragma unroll
    for (int j = 0; j < 8; ++j) {
      float v = acc[i][j] + bias[col0 + j];
      if (RELU) v = fmaxf(v, 0.f);
      out[j] = v;
    }
    *(float4*)(C + row * NN + col0)     = make_float4(out[0], out[1], out[2], out[3]);
    *(float4*)(C + row * NN + col0 + 4) = make_float4(out[4], out[5], out[6], out[7]);
  }
}

// Per 16 batch rows: logits = m @ Wc^T + bc ; y = argmax(logits) (softmax is
// monotonic, probs unused) ; z[e] = m . Wg[y, e, :] + bg[y, e] for e<16.
__global__ __launch_bounds__(256) void head_kernel(
    const float* __restrict__ m2, const float* __restrict__ Wc,
    const float* __restrict__ bc, const float* __restrict__ Wg,
    const float* __restrict__ bg, float* __restrict__ z_out,
    float* __restrict__ y_out) {
  __shared__ float sm[16][516];   // stride 516: float4-aligned, (4r+k)%32 banks
  __shared__ float sw[16][516];
  __shared__ float slog[16][17];
  __shared__ int sy[16];
  const int tid = threadIdx.x;
  const int r = tid >> 4;    // row within block
  const int c = tid & 15;    // class / latent index
  const size_t row0 = (size_t)blockIdx.x * 16;

  // stage 16 m-rows (32 KB) and full Wc (32 KB): 2048 float4 each, 8/thread
#pragma unroll
  for (int t = 0; t < 8; ++t) {
    int s = tid + t * 256;         // 0..2047
    int rr = s >> 7;               // 0..15
    int kc = (s & 127) << 2;       // 0..508
    *(float4*)&sm[rr][kc] = *(const float4*)(m2 + (row0 + rr) * 512 + kc);
    *(float4*)&sw[rr][kc] = *(const float4*)(Wc + (size_t)rr * 512 + kc);
  }
  __syncthreads();

  float dot = 0.f;
#pragma unroll 8
  for (int k = 0; k < 512; k += 4) {
    float4 a = *(const float4*)&sm[r][k];
    float4 w = *(const float4*)&sw[c][k];
    dot += a.x * w.x + a.y * w.y + a.z * w.z + a.w * w.w;
  }
  slog[r][c] = dot + bc[c];
  __syncthreads();

  if (c == 0) {
    // strict > keeps first max: matches np/jnp argmax tie-breaking
    float best = slog[r][0];
    int bi = 0;
#pragma unroll
    for (int j = 1; j < 16; ++j) {
      float v = slog[r][j];
      if (v > best) { best = v; bi = j; }
    }
    sy[r] = bi;
    y_out[row0 + r] = (float)bi;
  }
  __syncthreads();

  const int y = sy[r];
  const float* wg = Wg + ((size_t)y * 32 + c) * 512;  // Wg[y, c, :], c < 16 = mu part
  float zacc = 0.f;
#pragma unroll 8
  for (int k = 0; k < 512; k += 4) {
    float4 a = *(const float4*)&sm[r][k];
    float4 w = *(const float4*)(wg + k);
    zacc += a.x * w.x + a.y * w.y + a.z * w.z + a.w * w.w;
  }
  z_out[(row0 + r) * 16 + c] = zacc + bg[y * 32 + c];
}

extern "C" void kernel_launch(void* const* d_in, const int* in_sizes, int n_in,
                              void* d_out, int out_size, void* d_ws, size_t ws_size,
                              hipStream_t stream) {
  const float* x  = (const float*)d_in[0];
  const float* W0 = (const float*)d_in[1];
  const float* b0 = (const float*)d_in[2];
  const float* W1 = (const float*)d_in[3];
  const float* b1 = (const float*)d_in[4];
  const float* W2 = (const float*)d_in[5];
  const float* b2 = (const float*)d_in[6];
  const float* Wc = (const float*)d_in[7];
  const float* bc = (const float*)d_in[8];
  const float* Wg = (const float*)d_in[9];
  const float* bg = (const float*)d_in[10];

  float* m0 = (float*)d_ws;                       // 65536*512 floats = 128 MB
  float* m1 = m0 + (size_t)MM * KK;               // second 128 MB
  float* z_out = (float*)d_out;                   // 65536*16 floats
  float* y_out = z_out + (size_t)MM * 16;         // 65536 floats (argmax as float)

  dim3 grid(MM / BM, NN / BN);
  gemm_bias_kernel<true ><<<grid, 256, 0, stream>>>(x,  W0, b0, m0);
  gemm_bias_kernel<true ><<<grid, 256, 0, stream>>>(m0, W1, b1, m1);
  gemm_bias_kernel<false><<<grid, 256, 0, stream>>>(m1, W2, b2, m0);
  head_kernel<<<MM / 16, 256, 0, stream>>>(m0, Wc, bc, Wg, bg, z_out, y_out);
}